// Round 7
// baseline (308.003 us; speedup 1.0000x reference)
//
#include <hip/hip_runtime.h>

// SlotAttention on MI355X (gfx950).
// R6: pass-fusion round. gemm_qkv stages A (d or s) as RAW F32 via
// global_load_lds and converts to bf16 in-register (deletes the d-convert
// pass, 201 MB of HBM). Q projection merged as 16 extra blocks of the same
// kernel (deletes gemm128). cvt_all shrinks to the three weight matrices.
// GEMM geometry = R5 (256x128 tile, 4 waves, 2 blocks/CU, 2-slot dbuf,
// stage-early / drain-late): measured-equivalent of all 5 schedule variants.

#define TS 64
#define TD 4096
#define BATCH 8
#define HC 1024
#define NHEAD 16
#define MD (TD*BATCH)   // 32768
#define MS (TS*BATCH)   // 512
#define NCHUNK 8
#define CHTOK (TD/NCHUNK) // 512

typedef __attribute__((ext_vector_type(8))) __bf16 bf16x8;
typedef __attribute__((ext_vector_type(4))) float f32x4;
typedef __attribute__((ext_vector_type(4))) unsigned short u16x4;
typedef __attribute__((ext_vector_type(8))) unsigned short u16x8;

__device__ __forceinline__ unsigned short f2bf(float x){
  union { float f; unsigned u; } v; v.f = x;
  unsigned r = v.u + 0x7FFFu + ((v.u >> 16) & 1u);
  return (unsigned short)(r >> 16);
}

__device__ __forceinline__ void gll16(const void* g, void* l){
  __builtin_amdgcn_global_load_lds((__attribute__((address_space(1))) void*)g,
                                   (__attribute__((address_space(3))) void*)l, 16, 0, 0);
}

// f32->bf16 convert for the three weight matrices only (12 MB).
__global__ void cvt_w(const float* __restrict__ wq, const float* __restrict__ wk,
                      const float* __restrict__ wv,
                      unsigned short* __restrict__ wqb, unsigned short* __restrict__ wkb,
                      unsigned short* __restrict__ wvb){
  long i = (long)blockIdx.x * 256 + threadIdx.x;   // 786432 f32x4 units
  const float* src; unsigned short* dst; long off;
  if (i < 262144L)      { src = wq; dst = wqb; off = i; }
  else if (i < 524288L) { src = wk; dst = wkb; off = i - 262144L; }
  else                  { src = wv; dst = wvb; off = i - 524288L; }
  f32x4 f = ((const f32x4*)src)[off];
  u16x4 o;
  o[0] = f2bf(f[0]); o[1] = f2bf(f[1]); o[2] = f2bf(f[2]); o[3] = f2bf(f[3]);
  ((u16x4*)dst)[off] = o;
}

// ---------------------------------------------------------------------------
// Unified QKV GEMM. Blocks 0..2047: C_kv[32768 x 2048] = d_f32 @ [Wk;Wv]^T;
// blocks 2048..2063: Q[512 x 1024] = s_f32 @ Wq^T. bf16 outputs + bias.
// Tile 256x128, 4 waves (2Mx2N), per-wave 128x64, BK=32.
// A staged as F32 (32 KB/slot, 128B rows, chunk^row&7 XOR swizzle, 2-way max);
// B staged bf16 (8 KB/slot, R5 layout). 2 slots = 80 KB -> 2 blocks/CU.
// Per K-tile: STAGE(t+1)->other slot first, then 16 f32-pair ds_reads +
// in-reg cvt + 4 bf16 ds_reads + 32 MFMA, then __syncthreads (drain is
// ~2000 cyc after issue -> cheap).
// ---------------------------------------------------------------------------
__global__ __launch_bounds__(256, 2) void gemm_qkv(
    const float* __restrict__ dA,            // [32768][1024] f32
    const float* __restrict__ sA,            // [512][1024] f32
    const unsigned short* __restrict__ Wkv,  // [2048][1024] bf16 (Wk rows, then Wv)
    const unsigned short* __restrict__ Wq,   // [1024][1024] bf16
    const float* __restrict__ bq,
    const float* __restrict__ bk,
    const float* __restrict__ bv,
    unsigned short* __restrict__ Qout,
    unsigned short* __restrict__ Kout,
    unsigned short* __restrict__ Vout)
{
  __shared__ float          As[2][256*32];   // 32 KB per slot (f32)
  __shared__ unsigned short Bs[2][128*32];   //  8 KB per slot (bf16)

  const int nwg = gridDim.x;                 // 2064 (multiple of 8)
  const int cpx = nwg >> 3;                  // 258
  const int orig = blockIdx.x;
  const int wg = (orig & 7) * cpx + (orig >> 3);   // bijective XCD swizzle
  const int tid = threadIdx.x;
  const int lane = tid & 63, w = tid >> 6;   // 4 waves
  const int l15 = lane & 15, lg = lane >> 4;
  const int wm = w >> 1, wn = w & 1;

  const bool isQ = (wg >= 2048);
  int mt, nt;
  const float* Abase; const unsigned short* Wbase;
  if (!isQ){ mt = wg >> 4; nt = wg & 15; Abase = dA; Wbase = Wkv; }
  else     { int qi = wg - 2048; mt = qi >> 3; nt = qi & 7; Abase = sA; Wbase = Wq; }

  // ---- A staging (f32): 8 gll16/wave, each covers 8 rows x 128B.
  // LDS chunk position p = lane&7, row-in-group = lane>>3; src chunk = p ^ (row&7).
  const int a_r = lane >> 3;                  // 0..7
  const unsigned a_sw = (unsigned)(((lane & 7) ^ a_r) << 4);
  const char* aS = (const char*)(Abase + (size_t)mt*256*1024) + a_sw;
  unsigned a_src[8]; unsigned a_dst[8];
  #pragma unroll
  for (int j = 0; j < 8; ++j){
    a_src[j] = (unsigned)((w*64 + j*8 + a_r) * 4096);   // + kt*128 + a_sw (in aS)
    a_dst[j] = (unsigned)((w*64 + j*8) * 128);          // wave-uniform
  }

  // ---- B staging (bf16): 2 gll16/wave, each covers 16 rows x 64B (R5 layout).
  const int b_r = lane >> 2;                  // 0..15
  const unsigned b_sw = (unsigned)(((lane & 3) ^ ((lane >> 3) & 3)) << 4);
  const char* bS = (const char*)Wbase + (size_t)(nt*128) * 2048 + b_sw;
  unsigned b_src[2]; unsigned b_dst[2];
  #pragma unroll
  for (int j = 0; j < 2; ++j){
    b_src[j] = (unsigned)((j*64 + w*16 + b_r) * 2048);  // + kt*64 + b_sw (in bS)
    b_dst[j] = (unsigned)((j*64 + w*16) * 64);
  }

  #define STAGE(t_, buf_) { \
    const unsigned koA = (unsigned)(t_) * 128; \
    const unsigned koB = (unsigned)(t_) * 64; \
    char* dA_ = (char*)&As[buf_][0]; char* dB_ = (char*)&Bs[buf_][0]; \
    _Pragma("unroll") \
    for (int j = 0; j < 8; ++j) gll16(aS + a_src[j] + koA, dA_ + a_dst[j]); \
    _Pragma("unroll") \
    for (int j = 0; j < 2; ++j) gll16(bS + b_src[j] + koB, dB_ + b_dst[j]); \
    __builtin_amdgcn_sched_barrier(0); }

  // ---- fragment read offsets.
  // A (f32, 128B rows): frag m -> rows wm*128+m*16+l15, k-chunks {2lg,2lg+1}^ (l15&7)
  const unsigned arow = (unsigned)(wm*128 + l15) * 128;
  const unsigned ac0 = (unsigned)(((2*lg    ) ^ (l15 & 7)) << 4);
  const unsigned ac1 = (unsigned)(((2*lg + 1) ^ (l15 & 7)) << 4);
  // B (bf16, 64B rows): R5 pattern
  const unsigned boff = (unsigned)(wn*64 + l15) * 64 + (unsigned)((lg ^ ((l15 >> 1) & 3)) << 4);

  const f32x4 fz = {0.f, 0.f, 0.f, 0.f};
  f32x4 acc[8][4];
  #pragma unroll
  for (int m = 0; m < 8; ++m)
    #pragma unroll
    for (int n = 0; n < 4; ++n) acc[m][n] = fz;

  #define TILE(buf_) { \
    const char* as_ = (const char*)&As[buf_][0]; \
    const char* bs_ = (const char*)&Bs[buf_][0]; \
    bf16x8 af[8]; bf16x8 bfr[4]; \
    _Pragma("unroll") \
    for (int m = 0; m < 8; ++m){ \
      f32x4 u = *(const f32x4*)(as_ + arow + m*2048u + ac0); \
      f32x4 v = *(const f32x4*)(as_ + arow + m*2048u + ac1); \
      bf16x8 t; \
      t[0] = (__bf16)u[0]; t[1] = (__bf16)u[1]; t[2] = (__bf16)u[2]; t[3] = (__bf16)u[3]; \
      t[4] = (__bf16)v[0]; t[5] = (__bf16)v[1]; t[6] = (__bf16)v[2]; t[7] = (__bf16)v[3]; \
      af[m] = t; \
    } \
    _Pragma("unroll") \
    for (int n = 0; n < 4; ++n) bfr[n] = *(const bf16x8*)(bs_ + boff + n*1024u); \
    __builtin_amdgcn_s_setprio(1); \
    _Pragma("unroll") \
    for (int m = 0; m < 8; ++m) \
      _Pragma("unroll") \
      for (int n = 0; n < 4; ++n) \
        acc[m][n] = __builtin_amdgcn_mfma_f32_16x16x32_bf16(af[m], bfr[n], acc[m][n], 0, 0, 0); \
    __builtin_amdgcn_s_setprio(0); }

  // ---- prologue
  STAGE(0, 0)
  __syncthreads();

  // ---- main loop: 32 K-tiles, 2 per iteration
  #pragma unroll 1
  for (int tp = 0; tp < 16; ++tp){
    STAGE(2*tp + 1, 1)
    TILE(0)
    __syncthreads();
    if (tp < 15) STAGE(2*tp + 2, 0)
    TILE(1)
    __syncthreads();
  }

  // ---- epilogue: bias + bf16 store (all outputs stride 1024)
  int ccol; unsigned short* Cb; const float* bias;
  if (isQ)          { Cb = Qout; bias = bq; ccol = nt*128 + wn*64; }
  else if (nt < 8)  { Cb = Kout; bias = bk; ccol = nt*128 + wn*64; }
  else              { Cb = Vout; bias = bv; ccol = (nt - 8)*128 + wn*64; }
  float bvv[4];
  #pragma unroll
  for (int nf = 0; nf < 4; ++nf) bvv[nf] = bias[ccol + nf*16 + l15];
  #pragma unroll
  for (int mf = 0; mf < 8; ++mf){
    #pragma unroll
    for (int r = 0; r < 4; ++r){
      size_t row = (size_t)(mt*256 + wm*128 + mf*16 + lg*4 + r);
      __bf16* cp = (__bf16*)(Cb + row*1024 + ccol);
      #pragma unroll
      for (int nf = 0; nf < 4; ++nf)
        cp[nf*16 + l15] = (__bf16)(acc[mf][nf][r] + bvv[nf]);
    }
  }
  #undef STAGE
  #undef TILE
}

// one block per (b*16+h, chunk). 256 threads = 4 waves; wave w owns slots [16w,16w+16).
__global__ __launch_bounds__(256) void attn_kernel(
    const unsigned short* __restrict__ Q,
    const unsigned short* __restrict__ K,
    const unsigned short* __restrict__ V,
    float* __restrict__ P)
{
  __shared__ unsigned short Qs[64*64];
  __shared__ unsigned short Ks[64*64];
  __shared__ unsigned short Vt[80*64];
  __shared__ unsigned short Al[64*64];
  __shared__ float red[256];

  const int bh = blockIdx.x;
  const int chunk = blockIdx.y;
  const int bb = bh >> 4, h = bh & 15;
  const int tid = threadIdx.x;
  const int lane = tid & 63, w = tid >> 6;
  const int l15 = lane & 15, lg = lane >> 4;
  const int lrow = lane >> 3, lch = (lane & 7) << 4;

  for (int i = tid; i < 16*64; i += 256){
    int r = i >> 6;
    Vt[(64 + r)*64 + (i & 63)] = (r == 0) ? (unsigned short)0x3F80 : (unsigned short)0;
  }

  #pragma unroll
  for (int j = 0; j < 2; ++j){
    int row = w*16 + j*8 + lrow;
    int sw = lch ^ ((row & 7) << 4);
    const char* g = (const char*)Q + (size_t)(row*BATCH + bb)*2048 + h*128 + sw;
    gll16(g, (char*)Qs + (w*16 + j*8)*128);
  }

  const f32x4 fz = {0.f, 0.f, 0.f, 0.f};
  f32x4 acc[5];
  #pragma unroll
  for (int nb = 0; nb < 5; ++nb) acc[nb] = fz;

  const int vtok = tid >> 2;
  const int vcg  = tid & 3;
  const int t0 = chunk * CHTOK;

  for (int tt = 0; tt < CHTOK/64; ++tt){
    const int tb = t0 + tt*64;
    #pragma unroll
    for (int j = 0; j < 2; ++j){
      int row = w*16 + j*8 + lrow;
      int sw = lch ^ ((row & 7) << 4);
      const char* g = (const char*)K + (size_t)((size_t)(tb + row)*BATCH + bb)*2048 + h*128 + sw;
      gll16(g, (char*)Ks + (w*16 + j*8)*128);
    }
    const char* vg = (const char*)V + (size_t)((size_t)(tb + vtok)*BATCH + bb)*2048 + h*128 + vcg*32;
    u16x8 v0 = *(const u16x8*)vg;
    u16x8 v1 = *(const u16x8*)(vg + 16);
    __syncthreads();

    bf16x8 qa[2];
    #pragma unroll
    for (int kk = 0; kk < 2; ++kk){
      int row = w*16 + l15;
      qa[kk] = *(const bf16x8*)((const char*)Qs + row*128 + ((lg*16 + kk*64) ^ ((row & 7) << 4)));
    }
    float e[4][4];
    #pragma unroll
    for (int nb = 0; nb < 4; ++nb){
      f32x4 s = fz;
      #pragma unroll
      for (int kk = 0; kk < 2; ++kk){
        int row = nb*16 + l15;
        bf16x8 kb = *(const bf16x8*)((const char*)Ks + row*128 + ((lg*16 + kk*64) ^ ((row & 7) << 4)));
        s = __builtin_amdgcn_mfma_f32_16x16x32_bf16(qa[kk], kb, s, 0, 0, 0);
      }
      #pragma unroll
      for (int r = 0; r < 4; ++r) e[nb][r] = __expf(s[r] * 0.125f);
    }
    #pragma unroll
    for (int nb = 0; nb < 4; ++nb){
      float cp = e[nb][0] + e[nb][1] + e[nb][2] + e[nb][3];
      cp += __shfl_xor(cp, 16);
      cp += __shfl_xor(cp, 32);
      if (lg == 0) red[w*64 + nb*16 + l15] = cp;
    }
    __syncthreads();

    #pragma unroll
    for (int nb = 0; nb < 4; ++nb){
      int col = nb*16 + l15;
      float dn = red[col] + red[64 + col] + red[128 + col] + red[192 + col];
      float inv = 1.0f / dn;
      #pragma unroll
      for (int r = 0; r < 4; ++r){
        int row = w*16 + lg*4 + r;
        Al[row*64 + ((((2*col)) ^ ((row & 7) << 4)) >> 1)] = f2bf(e[nb][r] * inv);
      }
    }
    #pragma unroll
    for (int ee = 0; ee < 8; ++ee){
      int c0 = vcg*16 + ee;
      int sw0 = (((c0 & 7) ^ (c0 >> 3)) & 7) << 4;
      Vt[c0*64 + (((2*vtok) ^ sw0) >> 1)] = v0[ee];
    }
    #pragma unroll
    for (int ee = 0; ee < 8; ++ee){
      int c1 = vcg*16 + 8 + ee;
      int sw1 = (((c1 & 7) ^ (c1 >> 3)) & 7) << 4;
      Vt[c1*64 + (((2*vtok) ^ sw1) >> 1)] = v1[ee];
    }
    __syncthreads();

    bf16x8 aa[2];
    #pragma unroll
    for (int kk = 0; kk < 2; ++kk){
      int row = w*16 + l15;
      aa[kk] = *(const bf16x8*)((const char*)Al + row*128 + ((lg*16 + kk*64) ^ ((row & 7) << 4)));
    }
    #pragma unroll
    for (int nb = 0; nb < 5; ++nb){
      #pragma unroll
      for (int kk = 0; kk < 2; ++kk){
        int row = nb*16 + l15;
        int sw = (((row & 7) ^ (row >> 3)) & 7) << 4;
        bf16x8 vb = *(const bf16x8*)((const char*)Vt + row*128 + ((lg*16 + kk*64) ^ sw));
        acc[nb] = __builtin_amdgcn_mfma_f32_16x16x32_bf16(aa[kk], vb, acc[nb], 0, 0, 0);
      }
    }
  }

  float* Pb = P + (size_t)(bh*NCHUNK + chunk) * 64 * 80;
  #pragma unroll
  for (int nb = 0; nb < 5; ++nb){
    #pragma unroll
    for (int r = 0; r < 4; ++r){
      int s = w*16 + lg*4 + r;
      Pb[(size_t)s*80 + nb*16 + l15] = acc[nb][r];
    }
  }
}

__global__ void reduce_out(const float* __restrict__ P, float* __restrict__ out){
  int flat = blockIdx.x * 256 + threadIdx.x;
  int c = flat & 63, s = (flat >> 6) & 63, bh = flat >> 12;
  int bb = bh >> 4, h = bh & 15;
  float sc = 0.f, sn = 0.f;
  #pragma unroll
  for (int ch = 0; ch < NCHUNK; ++ch){
    const float* base = P + ((size_t)(bh*NCHUNK + ch)*64 + s)*80;
    sc += base[c];
    sn += base[64];
  }
  out[((size_t)s*BATCH + bb)*1024 + h*64 + c] = sc / (sn + 0.001f);
}

extern "C" void kernel_launch(void* const* d_in, const int* in_sizes, int n_in,
                              void* d_out, int out_size, void* d_ws, size_t ws_size,
                              hipStream_t stream)
{
  const float* s  = (const float*)d_in[0];
  const float* d  = (const float*)d_in[1];
  const float* Wq = (const float*)d_in[2];
  const float* bq = (const float*)d_in[3];
  const float* Wk = (const float*)d_in[4];
  const float* bk = (const float*)d_in[5];
  const float* Wv = (const float*)d_in[6];
  const float* bv = (const float*)d_in[7];
  float* out = (float*)d_out;

  char* ws = (char*)d_ws;
  unsigned short* wqb = (unsigned short*)(ws + 68157440);    //  2,097,152
  unsigned short* wkb = (unsigned short*)(ws + 70254592);    //  2,097,152 (Wk rows 0..1023)
  unsigned short* wvb = (unsigned short*)(ws + 72351744);    //  2,097,152 (Wv rows = wkb rows 1024..2047)
  unsigned short* Qw  = (unsigned short*)(ws + 74448896);    //  1,048,576
  unsigned short* Kw  = (unsigned short*)(ws + 75497472);    // 67,108,864
  unsigned short* Vw  = (unsigned short*)(ws + 142606336);   // 67,108,864
  float*          Pw  = (float*)(ws + 209715200);            // 20,971,520

  (void)in_sizes; (void)n_in; (void)out_size; (void)ws_size;

  cvt_w<<<3072, 256, 0, stream>>>(Wq, Wk, Wv, wqb, wkb, wvb);

  gemm_qkv<<<2064, 256, 0, stream>>>(d, s, wkb, wqb, bq, bk, bv, Qw, Kw, Vw);

  attn_kernel<<<dim3(128, NCHUNK), 256, 0, stream>>>(Qw, Kw, Vw, Pw);

  reduce_out<<<(TS*BATCH*HC)/256, 256, 0, stream>>>(Pw, out);
}

// Round 8
// 264.694 us; speedup vs baseline: 1.1636x; 1.1636x over previous
//
#include <hip/hip_runtime.h>

// SlotAttention on MI355X (gfx950).
// R7: gemm_kv computes K AND V columns from ONE staged A-tile (256x256
// output tile spanning both halves of [Wk;Wv]) -> staged bytes per FLOP
// halved for A. Diagnosis R2-R5: all schedules ingest-bound at ~15 B/cyc/CU
// (L2->CU staging stream), so intensity, not scheduling, is the lever.
// Schedule/swizzle = R5's proven race-free, zero-conflict pattern.

#define TS 64
#define TD 4096
#define BATCH 8
#define HC 1024
#define NHEAD 16
#define MD (TD*BATCH)   // 32768
#define MS (TS*BATCH)   // 512
#define NCHUNK 8
#define CHTOK (TD/NCHUNK) // 512

typedef __attribute__((ext_vector_type(8))) __bf16 bf16x8;
typedef __attribute__((ext_vector_type(4))) float f32x4;
typedef __attribute__((ext_vector_type(4))) unsigned short u16x4;
typedef __attribute__((ext_vector_type(8))) unsigned short u16x8;

__device__ __forceinline__ unsigned short f2bf(float x){
  union { float f; unsigned u; } v; v.f = x;
  unsigned r = v.u + 0x7FFFu + ((v.u >> 16) & 1u);
  return (unsigned short)(r >> 16);
}

__device__ __forceinline__ void gll16(const void* g, void* l){
  __builtin_amdgcn_global_load_lds((__attribute__((address_space(1))) void*)g,
                                   (__attribute__((address_space(3))) void*)l, 16, 0, 0);
}

// Fused f32->bf16 convert for all five inputs (one launch).
__global__ void cvt_all(const float* __restrict__ d, const float* __restrict__ s,
                        const float* __restrict__ wq, const float* __restrict__ wk,
                        const float* __restrict__ wv,
                        unsigned short* __restrict__ dbf, unsigned short* __restrict__ sbf,
                        unsigned short* __restrict__ wqb, unsigned short* __restrict__ wkb,
                        unsigned short* __restrict__ wvb){
  long i = (long)blockIdx.x * 256 + threadIdx.x;
  const float* src; unsigned short* dst; long off;
  if (i < 8388608L)      { src = d;  dst = dbf; off = i; }
  else if (i < 8519680L) { src = s;  dst = sbf; off = i - 8388608L; }
  else if (i < 8781824L) { src = wq; dst = wqb; off = i - 8519680L; }
  else if (i < 9043968L) { src = wk; dst = wkb; off = i - 8781824L; }
  else                   { src = wv; dst = wvb; off = i - 9043968L; }
  f32x4 f = ((const f32x4*)src)[off];
  u16x4 o;
  o[0] = f2bf(f[0]); o[1] = f2bf(f[1]); o[2] = f2bf(f[2]); o[3] = f2bf(f[3]);
  ((u16x4*)dst)[off] = o;
}

// ---------------------------------------------------------------------------
// Fused K|V GEMM, A-reuse version.
// Block (mt, nt): A rows [mt*256, +256); outputs K[:, nt*128..+128) AND
// V[:, nt*128..+128). B-tile local rows 0..127 = Wk rows nt*128..;
// 128..255 = Wv rows nt*128.. (= Wkv rows 1024+nt*128..).
// 512 threads = 8 waves (2M x 4N): wave (wm,wn), wn<2 -> K half, wn>=2 -> V.
// BK=32; LDS = (A 16KB + B 16KB) x 2 slots = 64KB -> 2 blocks/CU.
// Per K-tile per wave: 4 gll16 staged into opposite slot (issued first),
// 12 ds_read_b128 + 32 MFMA, one __syncthreads.
// 64B LDS rows, chunk XOR (row>>1)&3 swizzle (0 conflicts, R5-verified).
// ---------------------------------------------------------------------------
__global__ __launch_bounds__(512, 2) void gemm_kv(
    const unsigned short* __restrict__ A,     // [32768][1024] bf16
    const unsigned short* __restrict__ Wkv,   // [2048][1024] bf16 (Wk rows, then Wv)
    const float* __restrict__ bk,
    const float* __restrict__ bv,
    unsigned short* __restrict__ Kout,
    unsigned short* __restrict__ Vout)
{
  __shared__ unsigned short As[2][256*32];   // 16 KB per slot
  __shared__ unsigned short Bs[2][256*32];   // 16 KB per slot

  const int nwg = gridDim.x;                 // 1024 (multiple of 8)
  const int cpx = nwg >> 3;
  const int orig = blockIdx.x;
  const int wg = (orig & 7) * cpx + (orig >> 3);   // bijective XCD swizzle
  const int mt = wg >> 3, nt = wg & 7;       // 128 x 8 tiles
  const int tid = threadIdx.x;
  const int lane = tid & 63, w = tid >> 6;   // 8 waves
  const int l15 = lane & 15, lg = lane >> 4;
  const int wm = w >> 2, wn = w & 3;

  // ---- staging addressing: each gll16 covers 16 rows x 64B.
  // lane: row-in-group r4 = lane>>2, chunk pos = lane&3,
  // source chunk = pos ^ ((r4>>1)&3)  (pre-swizzled global source).
  const int r4 = lane >> 2;
  const unsigned sw4 = (unsigned)(((lane & 3) ^ ((lane >> 3) & 3)) << 4);
  size_t a_src[2]; size_t b_src[2]; unsigned s_dst[2];
  #pragma unroll
  for (int j = 0; j < 2; ++j){
    int la = w*32 + j*16 + r4;                       // 0..255
    a_src[j] = (size_t)(mt*256 + la) * 2048 + sw4;
    int gb = (la < 128) ? (nt*128 + la) : (1024 + nt*128 + (la - 128));
    b_src[j] = (size_t)gb * 2048 + sw4;
    s_dst[j] = (unsigned)((w*32 + j*16) * 64);       // wave-uniform
  }
  const char* aP = (const char*)A;
  const char* bP = (const char*)Wkv;

  #define STAGE(t_, buf_) { \
    const size_t ko = (size_t)(t_) * 64; \
    char* dA_ = (char*)&As[buf_][0]; char* dB_ = (char*)&Bs[buf_][0]; \
    gll16(aP + a_src[0] + ko, dA_ + s_dst[0]); \
    gll16(aP + a_src[1] + ko, dA_ + s_dst[1]); \
    gll16(bP + b_src[0] + ko, dB_ + s_dst[0]); \
    gll16(bP + b_src[1] + ko, dB_ + s_dst[1]); \
    __builtin_amdgcn_sched_barrier(0); }

  // ---- fragment read offsets: addr = row*64 + ((lg ^ ((l15>>1)&3))<<4)
  const unsigned ksel = (unsigned)((lg ^ ((l15 >> 1) & 3)) << 4);
  const unsigned aoff = (unsigned)(wm*128 + l15) * 64 + ksel;   // + mf*1024
  const unsigned boff = (unsigned)(wn*64  + l15) * 64 + ksel;   // + nf*1024

  const f32x4 fz = {0.f, 0.f, 0.f, 0.f};
  f32x4 acc[8][4];
  #pragma unroll
  for (int m = 0; m < 8; ++m)
    #pragma unroll
    for (int n = 0; n < 4; ++n) acc[m][n] = fz;

  #define TILE(buf_) { \
    const char* as_ = (const char*)&As[buf_][0]; \
    const char* bs_ = (const char*)&Bs[buf_][0]; \
    bf16x8 af[8], bfr[4]; \
    _Pragma("unroll") \
    for (int m = 0; m < 8; ++m) af[m] = *(const bf16x8*)(as_ + aoff + m*1024u); \
    _Pragma("unroll") \
    for (int n = 0; n < 4; ++n) bfr[n] = *(const bf16x8*)(bs_ + boff + n*1024u); \
    __builtin_amdgcn_s_setprio(1); \
    _Pragma("unroll") \
    for (int m = 0; m < 8; ++m) \
      _Pragma("unroll") \
      for (int n = 0; n < 4; ++n) \
        acc[m][n] = __builtin_amdgcn_mfma_f32_16x16x32_bf16(af[m], bfr[n], acc[m][n], 0, 0, 0); \
    __builtin_amdgcn_s_setprio(0); }

  // ---- prologue
  STAGE(0, 0)
  __syncthreads();

  // ---- main loop: 32 K-tiles, 2 per iteration (static buffer indices)
  #pragma unroll 1
  for (int tp = 0; tp < 16; ++tp){
    STAGE(2*tp + 1, 1)
    TILE(0)
    __syncthreads();
    if (tp < 15) STAGE(2*tp + 2, 0)
    TILE(1)
    __syncthreads();
  }

  // ---- epilogue: bias + bf16 store. wn<2 -> K columns, wn>=2 -> V columns.
  const int ccol = nt*128 + (wn & 1)*64;
  unsigned short* Cb = (wn < 2) ? Kout : Vout;
  const float* bias = (wn < 2) ? bk : bv;
  float bvv[4];
  #pragma unroll
  for (int nf = 0; nf < 4; ++nf) bvv[nf] = bias[ccol + nf*16 + l15];
  #pragma unroll
  for (int mf = 0; mf < 8; ++mf){
    #pragma unroll
    for (int r = 0; r < 4; ++r){
      size_t row = (size_t)(mt*256 + wm*128 + mf*16 + lg*4 + r);
      unsigned short* cp = Cb + row*1024 + ccol;
      #pragma unroll
      for (int nf = 0; nf < 4; ++nf)
        cp[nf*16 + l15] = f2bf(acc[mf][nf][r] + bvv[nf]);
    }
  }
  #undef STAGE
  #undef TILE
}

// ---------------------------------------------------------------------------
// 128^2 GEMM kept for Q (M=512): verified in R0.
// ---------------------------------------------------------------------------
__global__ __launch_bounds__(256) void gemm128(
    const unsigned short* __restrict__ A,
    const unsigned short* __restrict__ W,
    const float* __restrict__ bias,
    unsigned short* __restrict__ C)
{
  __shared__ unsigned short As[128*64];
  __shared__ unsigned short Bs[128*64];
  const int nwg = gridDim.x;
  const int cpx = nwg >> 3;
  const int orig = blockIdx.x;
  const int wg = (orig & 7) * cpx + (orig >> 3);
  const int mt = wg >> 3, nt = wg & 7;
  const int tid = threadIdx.x;
  const int lane = tid & 63, w = tid >> 6;
  const int l15 = lane & 15, lg = lane >> 4;
  const int wr = w >> 1, wc = w & 1;

  const int lrow = lane >> 3;
  const int lch  = (lane & 7) << 4;
  const char* pA[4]; const char* pB[4]; unsigned ldsoff[4];
  #pragma unroll
  for (int j = 0; j < 4; ++j){
    int row = w*32 + j*8 + lrow;
    int sw  = lch ^ ((row & 7) << 4);
    pA[j] = (const char*)A + (size_t)(mt*128 + row) * 2048 + sw;
    pB[j] = (const char*)W + (size_t)(nt*128 + row) * 2048 + sw;
    ldsoff[j] = (unsigned)(w*32 + j*8) * 128;
  }

  const f32x4 fz = {0.f, 0.f, 0.f, 0.f};
  f32x4 acc[4][4];
  #pragma unroll
  for (int m = 0; m < 4; ++m)
    #pragma unroll
    for (int n = 0; n < 4; ++n) acc[m][n] = fz;

  for (int kt = 0; kt < 16; ++kt){
    __syncthreads();
    #pragma unroll
    for (int j = 0; j < 4; ++j){
      gll16(pA[j] + (size_t)kt*128, (char*)As + ldsoff[j]);
      gll16(pB[j] + (size_t)kt*128, (char*)Bs + ldsoff[j]);
    }
    __syncthreads();
    #pragma unroll
    for (int kk = 0; kk < 2; ++kk){
      bf16x8 af[4], bfr[4];
      #pragma unroll
      for (int m = 0; m < 4; ++m){
        int row = wr*64 + m*16 + l15;
        af[m] = *(const bf16x8*)((const char*)As + row*128 + ((lg*16 + kk*64) ^ ((row & 7) << 4)));
      }
      #pragma unroll
      for (int n = 0; n < 4; ++n){
        int row = wc*64 + n*16 + l15;
        bfr[n] = *(const bf16x8*)((const char*)Bs + row*128 + ((lg*16 + kk*64) ^ ((row & 7) << 4)));
      }
      #pragma unroll
      for (int m = 0; m < 4; ++m)
        #pragma unroll
        for (int n = 0; n < 4; ++n)
          acc[m][n] = __builtin_amdgcn_mfma_f32_16x16x32_bf16(af[m], bfr[n], acc[m][n], 0, 0, 0);
    }
  }

  const int ccol0 = nt*128 + wc*64;
  float bv[4];
  #pragma unroll
  for (int n = 0; n < 4; ++n) bv[n] = bias[ccol0 + n*16 + l15];
  #pragma unroll
  for (int m = 0; m < 4; ++m){
    #pragma unroll
    for (int r = 0; r < 4; ++r){
      size_t row = (size_t)(mt*128 + wr*64 + m*16 + lg*4 + r);
      unsigned short* cp = C + row*1024 + ccol0;
      #pragma unroll
      for (int n = 0; n < 4; ++n)
        cp[n*16 + l15] = f2bf(acc[m][n][r] + bv[n]);
    }
  }
}

// one block per (b*16+h, chunk). 256 threads = 4 waves; wave w owns slots [16w,16w+16).
__global__ __launch_bounds__(256) void attn_kernel(
    const unsigned short* __restrict__ Q,
    const unsigned short* __restrict__ K,
    const unsigned short* __restrict__ V,
    float* __restrict__ P)
{
  __shared__ unsigned short Qs[64*64];
  __shared__ unsigned short Ks[64*64];
  __shared__ unsigned short Vt[80*64];
  __shared__ unsigned short Al[64*64];
  __shared__ float red[256];

  const int bh = blockIdx.x;
  const int chunk = blockIdx.y;
  const int bb = bh >> 4, h = bh & 15;
  const int tid = threadIdx.x;
  const int lane = tid & 63, w = tid >> 6;
  const int l15 = lane & 15, lg = lane >> 4;
  const int lrow = lane >> 3, lch = (lane & 7) << 4;

  for (int i = tid; i < 16*64; i += 256){
    int r = i >> 6;
    Vt[(64 + r)*64 + (i & 63)] = (r == 0) ? (unsigned short)0x3F80 : (unsigned short)0;
  }

  #pragma unroll
  for (int j = 0; j < 2; ++j){
    int row = w*16 + j*8 + lrow;
    int sw = lch ^ ((row & 7) << 4);
    const char* g = (const char*)Q + (size_t)(row*BATCH + bb)*2048 + h*128 + sw;
    gll16(g, (char*)Qs + (w*16 + j*8)*128);
  }

  const f32x4 fz = {0.f, 0.f, 0.f, 0.f};
  f32x4 acc[5];
  #pragma unroll
  for (int nb = 0; nb < 5; ++nb) acc[nb] = fz;

  const int vtok = tid >> 2;
  const int vcg  = tid & 3;
  const int t0 = chunk * CHTOK;

  for (int tt = 0; tt < CHTOK/64; ++tt){
    const int tb = t0 + tt*64;
    #pragma unroll
    for (int j = 0; j < 2; ++j){
      int row = w*16 + j*8 + lrow;
      int sw = lch ^ ((row & 7) << 4);
      const char* g = (const char*)K + (size_t)((size_t)(tb + row)*BATCH + bb)*2048 + h*128 + sw;
      gll16(g, (char*)Ks + (w*16 + j*8)*128);
    }
    const char* vg = (const char*)V + (size_t)((size_t)(tb + vtok)*BATCH + bb)*2048 + h*128 + vcg*32;
    u16x8 v0 = *(const u16x8*)vg;
    u16x8 v1 = *(const u16x8*)(vg + 16);
    __syncthreads();

    bf16x8 qa[2];
    #pragma unroll
    for (int kk = 0; kk < 2; ++kk){
      int row = w*16 + l15;
      qa[kk] = *(const bf16x8*)((const char*)Qs + row*128 + ((lg*16 + kk*64) ^ ((row & 7) << 4)));
    }
    float e[4][4];
    #pragma unroll
    for (int nb = 0; nb < 4; ++nb){
      f32x4 s = fz;
      #pragma unroll
      for (int kk = 0; kk < 2; ++kk){
        int row = nb*16 + l15;
        bf16x8 kb = *(const bf16x8*)((const char*)Ks + row*128 + ((lg*16 + kk*64) ^ ((row & 7) << 4)));
        s = __builtin_amdgcn_mfma_f32_16x16x32_bf16(qa[kk], kb, s, 0, 0, 0);
      }
      #pragma unroll
      for (int r = 0; r < 4; ++r) e[nb][r] = __expf(s[r] * 0.125f);
    }
    #pragma unroll
    for (int nb = 0; nb < 4; ++nb){
      float cp = e[nb][0] + e[nb][1] + e[nb][2] + e[nb][3];
      cp += __shfl_xor(cp, 16);
      cp += __shfl_xor(cp, 32);
      if (lg == 0) red[w*64 + nb*16 + l15] = cp;
    }
    __syncthreads();

    #pragma unroll
    for (int nb = 0; nb < 4; ++nb){
      int col = nb*16 + l15;
      float dn = red[col] + red[64 + col] + red[128 + col] + red[192 + col];
      float inv = 1.0f / dn;
      #pragma unroll
      for (int r = 0; r < 4; ++r){
        int row = w*16 + lg*4 + r;
        Al[row*64 + ((((2*col)) ^ ((row & 7) << 4)) >> 1)] = f2bf(e[nb][r] * inv);
      }
    }
    #pragma unroll
    for (int ee = 0; ee < 8; ++ee){
      int c0 = vcg*16 + ee;
      int sw0 = (((c0 & 7) ^ (c0 >> 3)) & 7) << 4;
      Vt[c0*64 + (((2*vtok) ^ sw0) >> 1)] = v0[ee];
    }
    #pragma unroll
    for (int ee = 0; ee < 8; ++ee){
      int c1 = vcg*16 + 8 + ee;
      int sw1 = (((c1 & 7) ^ (c1 >> 3)) & 7) << 4;
      Vt[c1*64 + (((2*vtok) ^ sw1) >> 1)] = v1[ee];
    }
    __syncthreads();

    bf16x8 aa[2];
    #pragma unroll
    for (int kk = 0; kk < 2; ++kk){
      int row = w*16 + l15;
      aa[kk] = *(const bf16x8*)((const char*)Al + row*128 + ((lg*16 + kk*64) ^ ((row & 7) << 4)));
    }
    #pragma unroll
    for (int nb = 0; nb < 5; ++nb){
      #pragma unroll
      for (int kk = 0; kk < 2; ++kk){
        int row = nb*16 + l15;
        int sw = (((row & 7) ^ (row >> 3)) & 7) << 4;
        bf16x8 vb = *(const bf16x8*)((const char*)Vt + row*128 + ((lg*16 + kk*64) ^ sw));
        acc[nb] = __builtin_amdgcn_mfma_f32_16x16x32_bf16(aa[kk], vb, acc[nb], 0, 0, 0);
      }
    }
  }

  float* Pb = P + (size_t)(bh*NCHUNK + chunk) * 64 * 80;
  #pragma unroll
  for (int nb = 0; nb < 5; ++nb){
    #pragma unroll
    for (int r = 0; r < 4; ++r){
      int s = w*16 + lg*4 + r;
      Pb[(size_t)s*80 + nb*16 + l15] = acc[nb][r];
    }
  }
}

__global__ void reduce_out(const float* __restrict__ P, float* __restrict__ out){
  int flat = blockIdx.x * 256 + threadIdx.x;
  int c = flat & 63, s = (flat >> 6) & 63, bh = flat >> 12;
  int bb = bh >> 4, h = bh & 15;
  float sc = 0.f, sn = 0.f;
  #pragma unroll
  for (int ch = 0; ch < NCHUNK; ++ch){
    const float* base = P + ((size_t)(bh*NCHUNK + ch)*64 + s)*80;
    sc += base[c];
    sn += base[64];
  }
  out[((size_t)s*BATCH + bb)*1024 + h*64 + c] = sc / (sn + 0.001f);
}

extern "C" void kernel_launch(void* const* d_in, const int* in_sizes, int n_in,
                              void* d_out, int out_size, void* d_ws, size_t ws_size,
                              hipStream_t stream)
{
  const float* s  = (const float*)d_in[0];
  const float* d  = (const float*)d_in[1];
  const float* Wq = (const float*)d_in[2];
  const float* bq = (const float*)d_in[3];
  const float* Wk = (const float*)d_in[4];
  const float* bk = (const float*)d_in[5];
  const float* Wv = (const float*)d_in[6];
  const float* bv = (const float*)d_in[7];
  float* out = (float*)d_out;

  char* ws = (char*)d_ws;
  unsigned short* dbf = (unsigned short*)(ws);               // 67,108,864
  unsigned short* sbf = (unsigned short*)(ws + 67108864);    //  1,048,576
  unsigned short* wqb = (unsigned short*)(ws + 68157440);    //  2,097,152
  unsigned short* wkb = (unsigned short*)(ws + 70254592);    //  2,097,152 (Wk rows 0..1023)
  unsigned short* wvb = (unsigned short*)(ws + 72351744);    //  2,097,152 (Wv rows = wkb rows 1024..2047)
  unsigned short* Qw  = (unsigned short*)(ws + 74448896);    //  1,048,576
  unsigned short* Kw  = (unsigned short*)(ws + 75497472);    // 67,108,864
  unsigned short* Vw  = (unsigned short*)(ws + 142606336);   // 67,108,864
  float*          Pw  = (float*)(ws + 209715200);            // 20,971,520

  (void)in_sizes; (void)n_in; (void)out_size; (void)ws_size;

  cvt_all<<<36352, 256, 0, stream>>>(d, s, Wq, Wk, Wv, dbf, sbf, wqb, wkb, wvb);

  gemm128<<<(MS/128)*8, 256, 0, stream>>>(sbf, wqb, bq, Qw);
  gemm_kv<<<(MD/256)*8, 512, 0, stream>>>(dbf, wkb, bk, bv, Kw, Vw);

  attn_kernel<<<dim3(128, NCHUNK), 256, 0, stream>>>(Qw, Kw, Vw, Pw);

  reduce_out<<<(TS*BATCH*HC)/256, 256, 0, stream>>>(Pw, out);
}